// Round 1
// baseline (165.784 us; speedup 1.0000x reference)
//
#include <hip/hip_runtime.h>
#include <math.h>

#define BATCH 256
#define NQ    1000
#define NC    80
#define NDET  300
#define THREADS 1024
#define SCORE_TH 0.05f

__global__ __launch_bounds__(THREADS) void rtdetr_post_kernel(
    const float* __restrict__ logits,   // [B, Q, C]
    const float* __restrict__ boxes,    // [B, Q, 4]
    const float* __restrict__ sizes,    // [B, 2] (h, w)
    float* __restrict__ out)            // scores[B*K] | labels[B*K] | boxes[B*K*4]
{
    __shared__ __align__(16) float s_score[NQ];   // masked scores
    __shared__ int   s_label[NQ];

    const int b = blockIdx.x;
    const int t = threadIdx.x;

    // ---------- Phase 1: per-query sigmoid-max / argmax (prob space) ----------
    if (t < NQ) {
        const float4* p = (const float4*)(logits + (size_t)b * NQ * NC + (size_t)t * NC);
        float best = -1.0f;   // probs are in (0,1)
        int bestc = 0;
        #pragma unroll 4
        for (int i = 0; i < NC / 4; ++i) {
            float4 v = p[i];
            // sigmoid per class, fp32, matching 1/(1+exp(-x)) elementwise
            float p0 = 1.0f / (1.0f + expf(-v.x));
            float p1 = 1.0f / (1.0f + expf(-v.y));
            float p2 = 1.0f / (1.0f + expf(-v.z));
            float p3 = 1.0f / (1.0f + expf(-v.w));
            // strict > keeps the FIRST index among equal probs (jnp.argmax semantics)
            if (p0 > best) { best = p0; bestc = 4 * i + 0; }
            if (p1 > best) { best = p1; bestc = 4 * i + 1; }
            if (p2 > best) { best = p2; bestc = 4 * i + 2; }
            if (p3 > best) { best = p3; bestc = 4 * i + 3; }
        }
        s_score[t] = (best > SCORE_TH) ? best : -1.0f;
        s_label[t] = bestc;
    }
    __syncthreads();

    // ---------- Phase 2: exact stable descending rank (all-pairs count) ----------
    if (t < NQ) {
        const float ms = s_score[t];
        int rank = 0;
        const float4* s4 = (const float4*)s_score;
        for (int j4 = 0; j4 < NQ / 4; ++j4) {
            float4 v = s4[j4];   // broadcast read across the wave (conflict-free)
            int j = 4 * j4;
            rank += (v.x > ms) || (v.x == ms && (j + 0) < t);
            rank += (v.y > ms) || (v.y == ms && (j + 1) < t);
            rank += (v.z > ms) || (v.z == ms && (j + 2) < t);
            rank += (v.w > ms) || (v.w == ms && (j + 3) < t);
        }
        if (rank < NDET) {
            const bool valid = ms > SCORE_TH;   // masked entries are -1.0 -> invalid
            float* out_scores = out;
            float* out_labels = out + (size_t)BATCH * NDET;
            float* out_boxes  = out + (size_t)2 * BATCH * NDET;
            const int o = b * NDET + rank;

            out_scores[o] = valid ? ms : 0.0f;
            out_labels[o] = valid ? (float)s_label[t] : -1.0f;

            float4 bx = ((const float4*)boxes)[b * NQ + t];   // cx, cy, w, h
            const float img_h = sizes[2 * b + 0];
            const float img_w = sizes[2 * b + 1];
            float4 ob;
            if (valid) {
                ob.x = (bx.x - 0.5f * bx.z) * img_w;
                ob.y = (bx.y - 0.5f * bx.w) * img_h;
                ob.z = (bx.x + 0.5f * bx.z) * img_w;
                ob.w = (bx.y + 0.5f * bx.w) * img_h;
            } else {
                ob = make_float4(0.0f, 0.0f, 0.0f, 0.0f);
            }
            ((float4*)out_boxes)[o] = ob;
        }
    }
}

extern "C" void kernel_launch(void* const* d_in, const int* in_sizes, int n_in,
                              void* d_out, int out_size, void* d_ws, size_t ws_size,
                              hipStream_t stream) {
    const float* logits = (const float*)d_in[0];   // [256,1000,80]
    const float* boxes  = (const float*)d_in[1];   // [256,1000,4]
    const float* sizes  = (const float*)d_in[2];   // [256,2]
    float* out = (float*)d_out;                    // 460800 floats

    rtdetr_post_kernel<<<BATCH, THREADS, 0, stream>>>(logits, boxes, sizes, out);
}